// Round 5
// baseline (214.600 us; speedup 1.0000x reference)
//
#include <hip/hip_runtime.h>
#include <cstdint>
#include <cstddef>

#define MB_   4096
#define NK_   8
#define DM_   1024
#define DT_   128

typedef __bf16 bf16;
typedef __bf16 bf16x8 __attribute__((ext_vector_type(8)));
typedef __bf16 bf16x4 __attribute__((ext_vector_type(4)));
typedef float  f32x4  __attribute__((ext_vector_type(4)));

__device__ __forceinline__ void gload_lds16(const void* g, void* l) {
  __builtin_amdgcn_global_load_lds(
      (__attribute__((address_space(1))) void*)g,
      (__attribute__((address_space(3))) void*)l,
      16, 0, 0);
}

// chunk swizzle: logical 16B-chunk c of row r lives at LDS chunk c ^ hsw(r).
// For 8-lane clock groups this spreads reads over all 8 16B slots / 128B.
__device__ __forceinline__ int hsw(int r) { return (r ^ (r >> 2)) & 3; }

// ---------------------------------------------------------------------------
__global__ void prep_pw_kernel(const float* __restrict__ pw, bf16* __restrict__ pwb) {
  size_t i = ((size_t)blockIdx.x * 256 + threadIdx.x) * 4;
  float4 f = *(const float4*)&pw[i];
  bf16x4 o = { (bf16)f.x, (bf16)f.y, (bf16)f.z, (bf16)f.w };
  *(bf16x4*)&pwb[i] = o;
}

__global__ void prep_wvt_kernel(const float* __restrict__ wvs, bf16* __restrict__ wvt) {
  int o = blockIdx.x * 256 + threadIdx.x;
  int d = o & 1023;
  int t = (o >> 10) & 127;
  int n = o >> 17;
  wvt[o] = (bf16)wvs[(size_t)n * 131072 + (size_t)d * 128 + t];
}

__global__ void fill_attns_kernel(float* __restrict__ out) {
  out[(size_t)33554432 + blockIdx.x * 256 + threadIdx.x] = 1.0f;
}

// ---------------------------------------------------------------------------
// GEMM1: v_s[n] = V_n[4096x1024](f32) @ WvT[n][128x1024]^T -> A2 scatter (bf16)
__global__ __launch_bounds__(256, 2) void gemm1_kernel(
    const float* __restrict__ vflat, const bf16* __restrict__ WvT,
    bf16* __restrict__ A2)
{
  __shared__ __align__(16) bf16 As[64 * 32];
  __shared__ __align__(16) bf16 Bs[128 * 32];
  const int tid  = threadIdx.x;
  const int wave = tid >> 6, lane = tid & 63;
  const int wm = wave >> 1, wn = wave & 1;
  const int n  = blockIdx.y;
  const int b0 = blockIdx.x * 64;

  const int r  = tid >> 2;
  const int hr = hsw(r);
  const int cs = (tid & 3) ^ hr;

  const float* ag = vflat + ((size_t)(n * MB_ + b0 + r)) * 1024 + (tid & 3) * 8;
  bf16* awr = As + r * 32 + cs * 8;
  const bf16* bg = WvT + (size_t)n * 131072 + (size_t)r * 1024 + cs * 8;
  char* bsb = (char*)Bs + wave * 1024;

  f32x4 acc[2][4] = {};
  const int krow = lane & 15;
  const int cch  = lane >> 4;
  const int swoff = ((cch ^ hsw(krow)) << 4);

  for (int kt = 0; kt < 32; ++kt) {
    const bf16* bptr = bg + kt * 32;
    gload_lds16(bptr,             bsb);
    gload_lds16(bptr + 64 * 1024, bsb + 4096);
    const float* aptr = ag + kt * 32;
    float4 f0 = *(const float4*)(aptr + 0);
    float4 f1 = *(const float4*)(aptr + 4);
    bf16x8 h0 = { (bf16)f0.x, (bf16)f0.y, (bf16)f0.z, (bf16)f0.w,
                  (bf16)f1.x, (bf16)f1.y, (bf16)f1.z, (bf16)f1.w };
    *(bf16x8*)awr = h0;
    __syncthreads();

    bf16x8 af[2], bfr[4];
    #pragma unroll
    for (int i = 0; i < 2; ++i)
      af[i] = *(const bf16x8*)((const char*)As + (wm * 32 + i * 16 + krow) * 64 + swoff);
    #pragma unroll
    for (int j = 0; j < 4; ++j)
      bfr[j] = *(const bf16x8*)((const char*)Bs + (wn * 64 + j * 16 + krow) * 64 + swoff);
    #pragma unroll
    for (int i = 0; i < 2; ++i)
      #pragma unroll
      for (int j = 0; j < 4; ++j)
        acc[i][j] = __builtin_amdgcn_mfma_f32_16x16x32_bf16(af[i], bfr[j], acc[i][j], 0, 0, 0);
    __syncthreads();
  }

  #pragma unroll
  for (int i = 0; i < 2; ++i) {
    #pragma unroll
    for (int j = 0; j < 4; ++j) {
      int t = wn * 64 + j * 16 + (lane & 15);
      #pragma unroll
      for (int rr = 0; rr < 4; ++rr) {
        int b = b0 + wm * 32 + i * 16 + (lane >> 4) * 4 + rr;
        size_t off = ((size_t)(n * 512 + (b >> 3))) * 1024 + (size_t)(b & 7) * 128 + t;
        A2[off] = (bf16)acc[i][j][rr];
      }
    }
  }
}

// ---------------------------------------------------------------------------
// GEMM2 pipelined + fused residual/stats epilogue.
// z = A2 @ PW^T + pb;  x = z + v  -> xout (bf16 ws or f32 d_out)
// per-LN-row partial sums (S,SS) over this block's n-quarter -> stats[rid][q].
// Tile 256x256, BK=32, 4 LDS bufs, 3-deep prefetch, counted vmcnt(8), swizzled.
template<bool ZB>
__global__ __launch_bounds__(512, 2) void gemm2p_kernel(
    const bf16* __restrict__ A2, const bf16* __restrict__ PW,
    const float* __restrict__ vres, const float* __restrict__ pb,
    void* __restrict__ xoutp, float2* __restrict__ stats)
{
  __shared__ __align__(16) bf16 As[4][8192];  // [buf][256*32]
  __shared__ __align__(16) bf16 Bs[4][8192];

  const int tid  = threadIdx.x;
  const int w    = tid >> 6;
  const int lane = tid & 63;
  const int wm   = w >> 2;       // 0..1
  const int wn   = w & 3;        // 0..3

  const int bid   = blockIdx.x;          // 0..511
  const int x     = bid & 7;
  const int local = bid >> 3;            // 0..63
  const int mt    = local & 15;
  const int nt    = x * 4 + (local >> 4);
  const int m0    = mt * 256;
  const int n0    = nt * 256;

  // staging: thread tid stages LDS chunk tid (16B) of each 128-row half-tile;
  // source chunk index swizzled so LDS slot (tid&3) holds logical chunk
  // (tid&3)^hsw(row).
  const int rS = tid >> 2;
  const int cS = (tid & 3) ^ hsw(rS);
  const char* aG0 = (const char*)A2 + (size_t)(m0 + rS) * 2048 + cS * 16;
  const char* aG1 = aG0 + (size_t)128 * 2048;
  const char* bG0 = (const char*)PW + (size_t)(n0 + rS) * 2048 + cS * 16;
  const char* bG1 = bG0 + (size_t)128 * 2048;

  #define STAGE_A(t) { char* d = (char*)As[(t) & 3] + tid * 16;            \
                       gload_lds16(aG0 + (t) * 64, d);                      \
                       gload_lds16(aG1 + (t) * 64, d + 8192); }
  #define STAGE_B(t) { char* d = (char*)Bs[(t) & 3] + tid * 16;            \
                       gload_lds16(bG0 + (t) * 64, d);                      \
                       gload_lds16(bG1 + (t) * 64, d + 8192); }

  // prologue: stage tiles 0,1,2 (12 loads); wait tile 0 (8 left in flight)
  STAGE_A(0); STAGE_B(0); STAGE_A(1); STAGE_B(1); STAGE_A(2); STAGE_B(2);
  asm volatile("s_waitcnt vmcnt(8)" ::: "memory");
  __builtin_amdgcn_sched_barrier(0);
  __builtin_amdgcn_s_barrier();

  f32x4 acc[8][4] = {};
  const int fr = lane & 15;
  const int g  = lane >> 4;
  // swizzled read: row byte base + chunk (g ^ hsw(fr))*16
  const int swoff = ((g ^ hsw(fr)) << 4);
  const int aRd = (wm * 128 + fr) * 64 + swoff;   // byte offset in As[buf]
  const int bRd = (wn * 64  + fr) * 64 + swoff;

  #pragma unroll 4
  for (int t = 0; t < 32; ++t) {
    const char* pA = (const char*)As[t & 3] + aRd;
    const char* pB = (const char*)Bs[t & 3] + bRd;

    // ---- phase 1 ----
    bf16x8 a[4], b[4];
    #pragma unroll
    for (int m = 0; m < 4; ++m) a[m] = *(const bf16x8*)(pA + m * 1024);
    #pragma unroll
    for (int n = 0; n < 4; ++n) b[n] = *(const bf16x8*)(pB + n * 1024);
    if (t < 29) STAGE_A(t + 3);
    __builtin_amdgcn_s_barrier();
    __builtin_amdgcn_s_setprio(1);
    #pragma unroll
    for (int m = 0; m < 4; ++m)
      #pragma unroll
      for (int n = 0; n < 4; ++n)
        acc[m][n] = __builtin_amdgcn_mfma_f32_16x16x32_bf16(a[m], b[n], acc[m][n], 0, 0, 0);
    __builtin_amdgcn_s_setprio(0);
    __builtin_amdgcn_s_barrier();

    // ---- phase 2 ----
    bf16x8 a2[4];
    #pragma unroll
    for (int m = 0; m < 4; ++m) a2[m] = *(const bf16x8*)(pA + (4 + m) * 1024);
    if (t < 29) STAGE_B(t + 3);
    __builtin_amdgcn_s_barrier();
    __builtin_amdgcn_s_setprio(1);
    #pragma unroll
    for (int m = 0; m < 4; ++m)
      #pragma unroll
      for (int n = 0; n < 4; ++n)
        acc[4 + m][n] = __builtin_amdgcn_mfma_f32_16x16x32_bf16(a2[m], b[n], acc[4 + m][n], 0, 0, 0);
    __builtin_amdgcn_s_setprio(0);
    if (t < 29)       { asm volatile("s_waitcnt vmcnt(8)" ::: "memory"); }
    else if (t == 29) { asm volatile("s_waitcnt vmcnt(4)" ::: "memory"); }
    else if (t == 30) { asm volatile("s_waitcnt vmcnt(0)" ::: "memory"); }
    __builtin_amdgcn_sched_barrier(0);
    __builtin_amdgcn_s_barrier();
  }
  #undef STAGE_A
  #undef STAGE_B

  // ---- epilogue: x = acc + pb + v; write x; partial LN stats ----
  float pbv[4];
  #pragma unroll
  for (int n = 0; n < 4; ++n) pbv[n] = pb[n0 + wn * 64 + n * 16 + fr];

  float sthr[8][4], qthr[8][4];   // per-thread row partials over 4 n-frags
  #pragma unroll
  for (int m = 0; m < 8; ++m) {
    #pragma unroll
    for (int r = 0; r < 4; ++r) {
      int lrow = wm * 128 + m * 16 + g * 4 + r;
      const float* vrow = vres + (size_t)(m0 + lrow) * 8192 + n0 + wn * 64 + fr;
      float s = 0.0f, q2 = 0.0f;
      #pragma unroll
      for (int n = 0; n < 4; ++n) {
        float xv = acc[m][n][r] + pbv[n] + vrow[n * 16];
        acc[m][n][r] = xv;
        s += xv; q2 += xv * xv;
      }
      sthr[m][r] = s; qthr[m][r] = q2;
    }
  }
  // write x
  #pragma unroll
  for (int m = 0; m < 8; ++m) {
    #pragma unroll
    for (int n = 0; n < 4; ++n) {
      size_t coff = (size_t)(n0 + wn * 64 + n * 16 + fr);
      #pragma unroll
      for (int r = 0; r < 4; ++r) {
        size_t off = (size_t)(m0 + wm * 128 + m * 16 + g * 4 + r) * 8192 + coff;
        if (ZB) ((bf16*)xoutp)[off] = (bf16)acc[m][n][r];
        else    ((float*)xoutp)[off] = acc[m][n][r];
      }
    }
  }
  // reduce partials over the 16 fr lanes
  #pragma unroll
  for (int m = 0; m < 8; ++m)
    #pragma unroll
    for (int r = 0; r < 4; ++r) {
      float s = sthr[m][r], q2 = qthr[m][r];
      #pragma unroll
      for (int msk = 8; msk >= 1; msk >>= 1) {
        s  += __shfl_xor(s,  msk, 64);
        q2 += __shfl_xor(q2, msk, 64);
      }
      sthr[m][r] = s; qthr[m][r] = q2;
    }
  // LDS cross-wave reduce (reuse As storage)
  float* sredS = (float*)&As[0][0];      // [256][4]
  float* sredQ = sredS + 1024;           // [256][4]
  if (fr == 0) {
    #pragma unroll
    for (int m = 0; m < 8; ++m)
      #pragma unroll
      for (int r = 0; r < 4; ++r) {
        int lrow = wm * 128 + m * 16 + g * 4 + r;
        sredS[lrow * 4 + wn] = sthr[m][r];
        sredQ[lrow * 4 + wn] = qthr[m][r];
      }
  }
  __syncthreads();
  if (tid < 256) {
    float S  = sredS[tid * 4] + sredS[tid * 4 + 1] + sredS[tid * 4 + 2] + sredS[tid * 4 + 3];
    float SS = sredQ[tid * 4] + sredQ[tid * 4 + 1] + sredQ[tid * 4 + 2] + sredQ[tid * 4 + 3];
    int rid = (m0 + tid) * 8 + (nt >> 2);
    stats[(size_t)rid * 4 + (nt & 3)] = make_float2(S, SS);
  }
}

// ---------------------------------------------------------------------------
// LN apply: per LN row (bid = mrow*8+j), read 4 quarter stats + x, write out.
template<bool ZB>
__global__ __launch_bounds__(256) void ln_apply_kernel(
    const void* xin, const float2* __restrict__ stats,
    const float* __restrict__ gamma, const float* __restrict__ beta,
    float* outp)
{
  const int bid = blockIdx.x;          // 0..32767
  const int tid = threadIdx.x;
  float2 st0 = stats[(size_t)bid * 4 + 0];
  float2 st1 = stats[(size_t)bid * 4 + 1];
  float2 st2 = stats[(size_t)bid * 4 + 2];
  float2 st3 = stats[(size_t)bid * 4 + 3];
  float S  = st0.x + st1.x + st2.x + st3.x;
  float SS = st0.y + st1.y + st2.y + st3.y;
  float mu  = S * (1.0f / 1024.0f);
  float var = (SS - 1024.0f * mu * mu) * (1.0f / 1023.0f);
  var = var < 0.0f ? 0.0f : var;
  float rs = 1.0f / (sqrtf(var) + 1e-3f);

  const size_t base = (size_t)bid * 1024 + tid * 4;
  float4 xv;
  if (ZB) {
    bf16x4 xb = *(const bf16x4*)((const bf16*)xin + base);
    xv.x = (float)xb[0]; xv.y = (float)xb[1]; xv.z = (float)xb[2]; xv.w = (float)xb[3];
  } else {
    xv = *(const float4*)((const float*)xin + base);
  }
  float4 ga = *(const float4*)&gamma[tid * 4];
  float4 be = *(const float4*)&beta[tid * 4];
  float4 y;
  y.x = (xv.x - mu) * rs * ga.x + be.x;
  y.y = (xv.y - mu) * rs * ga.y + be.y;
  y.z = (xv.z - mu) * rs * ga.z + be.z;
  y.w = (xv.w - mu) * rs * ga.w + be.w;
  *(float4*)&outp[base] = y;
}

// ---------------------------------------------------------------------------
extern "C" void kernel_launch(void* const* d_in, const int* in_sizes, int n_in,
                              void* d_out, int out_size, void* d_ws, size_t ws_size,
                              hipStream_t stream) {
  const float* v     = (const float*)d_in[2];
  const float* wvs   = (const float*)d_in[5];
  const float* pw    = (const float*)d_in[6];
  const float* pb    = (const float*)d_in[7];
  const float* gamma = (const float*)d_in[8];
  const float* beta  = (const float*)d_in[9];
  float* out = (float*)d_out;

  // ws: PW bf16 16M | WvT bf16 2M | A2 bf16 8M | stats 1M | x bf16 64M
  const size_t OFF_WVT = 16777216;
  const size_t OFF_A2  = OFF_WVT + 2097152;
  const size_t OFF_ST  = OFF_A2 + 8388608;
  const size_t OFF_X   = OFF_ST + 1048576;
  const size_t NEED_ZB = OFF_X + 67108864;

  bf16*   PWb   = (bf16*)d_ws;
  bf16*   WvT   = (bf16*)((char*)d_ws + OFF_WVT);
  bf16*   A2    = (bf16*)((char*)d_ws + OFF_A2);
  float2* stats = (float2*)((char*)d_ws + OFF_ST);
  const bool zb = (ws_size >= NEED_ZB);
  void* xbuf = zb ? (void*)((char*)d_ws + OFF_X) : (void*)out;

  hipLaunchKernelGGL(prep_pw_kernel,    dim3(8192), dim3(256), 0, stream, pw, PWb);
  hipLaunchKernelGGL(prep_wvt_kernel,   dim3(4096), dim3(256), 0, stream, wvs, WvT);
  hipLaunchKernelGGL(fill_attns_kernel, dim3(128),  dim3(256), 0, stream, out);
  hipLaunchKernelGGL(gemm1_kernel, dim3(64, 8), dim3(256), 0, stream, v, WvT, A2);
  if (zb) {
    hipLaunchKernelGGL((gemm2p_kernel<true>),  dim3(512), dim3(512), 0, stream,
                       A2, PWb, v, pb, xbuf, stats);
    hipLaunchKernelGGL((ln_apply_kernel<true>),  dim3(32768), dim3(256), 0, stream,
                       xbuf, stats, gamma, beta, out);
  } else {
    hipLaunchKernelGGL((gemm2p_kernel<false>), dim3(512), dim3(512), 0, stream,
                       A2, PWb, v, pb, xbuf, stats);
    hipLaunchKernelGGL((ln_apply_kernel<false>), dim3(32768), dim3(256), 0, stream,
                       xbuf, stats, gamma, beta, out);
  }
}

// Round 7
// 200.975 us; speedup vs baseline: 1.0678x; 1.0678x over previous
//
#include <hip/hip_runtime.h>
#include <cstdint>
#include <cstddef>

#define MB_   4096
#define NK_   8
#define DM_   1024
#define DT_   128

typedef __bf16 bf16;
typedef __bf16 bf16x8 __attribute__((ext_vector_type(8)));
typedef __bf16 bf16x4 __attribute__((ext_vector_type(4)));
typedef float  f32x4  __attribute__((ext_vector_type(4)));

__device__ __forceinline__ void gload_lds16(const void* g, void* l) {
  __builtin_amdgcn_global_load_lds(
      (__attribute__((address_space(1))) void*)g,
      (__attribute__((address_space(3))) void*)l,
      16, 0, 0);
}

// chunk swizzle: logical 16B-chunk c of row r lives at LDS chunk c ^ hsw(r).
__device__ __forceinline__ int hsw(int r) { return (r ^ (r >> 2)) & 3; }

// ---------------------------------------------------------------------------
__global__ void prep_pw_kernel(const float* __restrict__ pw, bf16* __restrict__ pwb) {
  size_t i = ((size_t)blockIdx.x * 256 + threadIdx.x) * 4;
  float4 f = *(const float4*)&pw[i];
  bf16x4 o = { (bf16)f.x, (bf16)f.y, (bf16)f.z, (bf16)f.w };
  *(bf16x4*)&pwb[i] = o;
}

__global__ void prep_wvt_kernel(const float* __restrict__ wvs, bf16* __restrict__ wvt) {
  int o = blockIdx.x * 256 + threadIdx.x;
  int d = o & 1023;
  int t = (o >> 10) & 127;
  int n = o >> 17;
  wvt[o] = (bf16)wvs[(size_t)n * 131072 + (size_t)d * 128 + t];
}

__global__ void fill_attns_kernel(float* __restrict__ out) {
  out[(size_t)33554432 + blockIdx.x * 256 + threadIdx.x] = 1.0f;
}

// ---------------------------------------------------------------------------
// GEMM1: v_s[n] = V_n[4096x1024](f32) @ WvT[n][128x1024]^T -> A2 scatter (bf16)
__global__ __launch_bounds__(256, 2) void gemm1_kernel(
    const float* __restrict__ vflat, const bf16* __restrict__ WvT,
    bf16* __restrict__ A2)
{
  __shared__ __align__(16) bf16 As[64 * 32];
  __shared__ __align__(16) bf16 Bs[128 * 32];
  const int tid  = threadIdx.x;
  const int wave = tid >> 6, lane = tid & 63;
  const int wm = wave >> 1, wn = wave & 1;
  const int n  = blockIdx.y;
  const int b0 = blockIdx.x * 64;

  const int r  = tid >> 2;
  const int hr = hsw(r);
  const int cs = (tid & 3) ^ hr;

  const float* ag = vflat + ((size_t)(n * MB_ + b0 + r)) * 1024 + (tid & 3) * 8;
  bf16* awr = As + r * 32 + cs * 8;
  const bf16* bg = WvT + (size_t)n * 131072 + (size_t)r * 1024 + cs * 8;
  char* bsb = (char*)Bs + wave * 1024;

  f32x4 acc[2][4] = {};
  const int krow = lane & 15;
  const int cch  = lane >> 4;
  const int swoff = ((cch ^ hsw(krow)) << 4);

  for (int kt = 0; kt < 32; ++kt) {
    const bf16* bptr = bg + kt * 32;
    gload_lds16(bptr,             bsb);
    gload_lds16(bptr + 64 * 1024, bsb + 4096);
    const float* aptr = ag + kt * 32;
    float4 f0 = *(const float4*)(aptr + 0);
    float4 f1 = *(const float4*)(aptr + 4);
    bf16x8 h0 = { (bf16)f0.x, (bf16)f0.y, (bf16)f0.z, (bf16)f0.w,
                  (bf16)f1.x, (bf16)f1.y, (bf16)f1.z, (bf16)f1.w };
    *(bf16x8*)awr = h0;
    __syncthreads();

    bf16x8 af[2], bfr[4];
    #pragma unroll
    for (int i = 0; i < 2; ++i)
      af[i] = *(const bf16x8*)((const char*)As + (wm * 32 + i * 16 + krow) * 64 + swoff);
    #pragma unroll
    for (int j = 0; j < 4; ++j)
      bfr[j] = *(const bf16x8*)((const char*)Bs + (wn * 64 + j * 16 + krow) * 64 + swoff);
    #pragma unroll
    for (int i = 0; i < 2; ++i)
      #pragma unroll
      for (int j = 0; j < 4; ++j)
        acc[i][j] = __builtin_amdgcn_mfma_f32_16x16x32_bf16(af[i], bfr[j], acc[i][j], 0, 0, 0);
    __syncthreads();
  }

  #pragma unroll
  for (int i = 0; i < 2; ++i) {
    #pragma unroll
    for (int j = 0; j < 4; ++j) {
      int t = wn * 64 + j * 16 + (lane & 15);
      #pragma unroll
      for (int rr = 0; rr < 4; ++rr) {
        int b = b0 + wm * 32 + i * 16 + (lane >> 4) * 4 + rr;
        size_t off = ((size_t)(n * 512 + (b >> 3))) * 1024 + (size_t)(b & 7) * 128 + t;
        A2[off] = (bf16)acc[i][j][rr];
      }
    }
  }
}

// ---------------------------------------------------------------------------
// GEMM2 8-phase: x[4096][8192] = A2 @ PW^T + pb  (bf16 to ws or f32 to d_out).
// Tile 256x256, 32 sub-tiles of BK=32 (2 per iteration x 16 iterations),
// 4 LDS buffers, stages run 3 sub-tiles ahead, counted vmcnt(8) at sub-tile
// boundaries (T3+T4), setprio on MFMA (T5). 8 phases per iteration.
template<bool ZB>
__global__ __launch_bounds__(512, 2) void gemm2p8_kernel(
    const bf16* __restrict__ A2, const bf16* __restrict__ PW,
    const float* __restrict__ pb, void* __restrict__ xoutp)
{
  __shared__ __align__(16) bf16 As[4][8192];  // [buf][256 rows x 32 k] 16KB
  __shared__ __align__(16) bf16 Bs[4][8192];

  const int tid  = threadIdx.x;
  const int w    = tid >> 6;
  const int lane = tid & 63;
  const int wm   = w >> 2;       // 0..1
  const int wn   = w & 3;        // 0..3

  const int bid   = blockIdx.x;          // 0..511
  const int x     = bid & 7;
  const int local = bid >> 3;            // 0..63
  const int mt    = local & 15;
  const int nt    = x * 4 + (local >> 4);
  const int m0    = mt * 256;
  const int n0    = nt * 256;

  // staging: thread tid stages 16B chunk tid of each 128-row half (pre-swizzled src)
  const int rS = tid >> 2;
  const int cS = (tid & 3) ^ hsw(rS);
  const char* aG0 = (const char*)A2 + (size_t)(m0 + rS) * 2048 + cS * 16;
  const char* aG1 = aG0 + (size_t)128 * 2048;
  const char* bG0 = (const char*)PW + (size_t)(n0 + rS) * 2048 + cS * 16;
  const char* bG1 = bG0 + (size_t)128 * 2048;

  #define SA0(t) gload_lds16(aG0 + (size_t)(t) * 64, (char*)As[(t) & 3] + tid * 16)
  #define SA1(t) gload_lds16(aG1 + (size_t)(t) * 64, (char*)As[(t) & 3] + 8192 + tid * 16)
  #define SB0(t) gload_lds16(bG0 + (size_t)(t) * 64, (char*)Bs[(t) & 3] + tid * 16)
  #define SB1(t) gload_lds16(bG1 + (size_t)(t) * 64, (char*)Bs[(t) & 3] + 8192 + tid * 16)

  // prologue: sub-tiles 0,1,2 fully staged (12 loads); wait tile 0 (8 in flight)
  SA0(0); SA1(0); SB0(0); SB1(0);
  SA0(1); SA1(1); SB0(1); SB1(1);
  SA0(2); SA1(2); SB0(2); SB1(2);
  asm volatile("s_waitcnt vmcnt(8)" ::: "memory");
  __builtin_amdgcn_sched_barrier(0);
  __builtin_amdgcn_s_barrier();

  f32x4 acc[8][4] = {};
  const int fr = lane & 15;
  const int g  = lane >> 4;
  const int swoff = ((g ^ hsw(fr)) << 4);
  const int aRd = (wm * 128 + fr) * 64 + swoff;   // byte offset in As[buf]
  const int bRd = (wn * 64  + fr) * 64 + swoff;

  #define MFMA_Q(MB, NB)                                                     \
    { __builtin_amdgcn_s_setprio(1);                                         \
      _Pragma("unroll")                                                      \
      for (int m = 0; m < 4; ++m) {                                          \
        _Pragma("unroll")                                                    \
        for (int n = 0; n < 2; ++n)                                          \
          acc[(MB) + m][(NB) + n] = __builtin_amdgcn_mfma_f32_16x16x32_bf16( \
              a[m], b[(NB) + n], acc[(MB) + m][(NB) + n], 0, 0, 0);          \
      }                                                                      \
      __builtin_amdgcn_s_setprio(0); }

  #pragma unroll 1
  for (int i = 0; i < 16; ++i) {
    const int t0 = 2 * i, t1 = 2 * i + 1;
    const int sA = t0 + 3, sB = t0 + 4;
    const bool doA = (sA < 32), doB = (sB < 32);
    const char* pA0 = (const char*)As[t0 & 3] + aRd;
    const char* pB0 = (const char*)Bs[t0 & 3] + bRd;
    const char* pA1 = (const char*)As[t1 & 3] + aRd;
    const char* pB1 = (const char*)Bs[t1 & 3] + bRd;
    bf16x8 a[4], b[4];

    // ---------------- sub-tile t0 ----------------
    // ph0: A m0-3 + B n0-1 reads, stage A0(sA), MFMA (m0-3 x n0-1)
    #pragma unroll
    for (int m = 0; m < 4; ++m) a[m] = *(const bf16x8*)(pA0 + m * 1024);
    #pragma unroll
    for (int n = 0; n < 2; ++n) b[n] = *(const bf16x8*)(pB0 + n * 1024);
    if (doA) SA0(sA);
    __builtin_amdgcn_s_barrier();
    MFMA_Q(0, 0);
    __builtin_amdgcn_s_barrier();

    // ph1: B n2-3 reads, stage A1(sA), MFMA (m0-3 x n2-3)
    #pragma unroll
    for (int n = 0; n < 2; ++n) b[2 + n] = *(const bf16x8*)(pB0 + (2 + n) * 1024);
    if (doA) SA1(sA);
    __builtin_amdgcn_s_barrier();
    MFMA_Q(0, 2);
    __builtin_amdgcn_s_barrier();

    // ph2: A m4-7 reads, stage B0(sA), MFMA (m4-7 x n0-1)
    #pragma unroll
    for (int m = 0; m < 4; ++m) a[m] = *(const bf16x8*)(pA0 + (4 + m) * 1024);
    if (doA) SB0(sA);
    __builtin_amdgcn_s_barrier();
    MFMA_Q(4, 0);
    __builtin_amdgcn_s_barrier();

    // ph3: stage B1(sA), boundary vmcnt, MFMA (m4-7 x n2-3)
    if (doA) SB1(sA);
    if (i < 15) { asm volatile("s_waitcnt vmcnt(8)" ::: "memory"); }
    else        { asm volatile("s_waitcnt vmcnt(0)" ::: "memory"); }
    __builtin_amdgcn_sched_barrier(0);
    __builtin_amdgcn_s_barrier();
    MFMA_Q(4, 2);
    __builtin_amdgcn_s_barrier();

    // ---------------- sub-tile t1 ----------------
    // ph4
    #pragma unroll
    for (int m = 0; m < 4; ++m) a[m] = *(const bf16x8*)(pA1 + m * 1024);
    #pragma unroll
    for (int n = 0; n < 2; ++n) b[n] = *(const bf16x8*)(pB1 + n * 1024);
    if (doB) SA0(sB);
    __builtin_amdgcn_s_barrier();
    MFMA_Q(0, 0);
    __builtin_amdgcn_s_barrier();

    // ph5
    #pragma unroll
    for (int n = 0; n < 2; ++n) b[2 + n] = *(const bf16x8*)(pB1 + (2 + n) * 1024);
    if (doB) SA1(sB);
    __builtin_amdgcn_s_barrier();
    MFMA_Q(0, 2);
    __builtin_amdgcn_s_barrier();

    // ph6
    #pragma unroll
    for (int m = 0; m < 4; ++m) a[m] = *(const bf16x8*)(pA1 + (4 + m) * 1024);
    if (doB) SB0(sB);
    __builtin_amdgcn_s_barrier();
    MFMA_Q(4, 0);
    __builtin_amdgcn_s_barrier();

    // ph7
    if (doB) SB1(sB);
    if (i < 14)      { asm volatile("s_waitcnt vmcnt(8)" ::: "memory"); }
    else if (i == 14){ asm volatile("s_waitcnt vmcnt(4)" ::: "memory"); }
    __builtin_amdgcn_sched_barrier(0);
    __builtin_amdgcn_s_barrier();
    MFMA_Q(4, 2);
    __builtin_amdgcn_s_barrier();
  }
  #undef SA0
  #undef SA1
  #undef SB0
  #undef SB1
  #undef MFMA_Q

  // epilogue: x = acc + pb -> bf16 ws (or f32 d_out)
  #pragma unroll
  for (int m = 0; m < 8; ++m) {
    #pragma unroll
    for (int n = 0; n < 4; ++n) {
      int nn = n0 + wn * 64 + n * 16 + fr;
      float pbn = pb[nn];
      #pragma unroll
      for (int r = 0; r < 4; ++r) {
        int mm = m0 + wm * 128 + m * 16 + g * 4 + r;
        size_t off = (size_t)mm * 8192 + nn;
        float val = acc[m][n][r] + pbn;
        if (ZB) ((bf16*)xoutp)[off] = (bf16)val;
        else    ((float*)xoutp)[off] = val;
      }
    }
  }
}

// ---------------------------------------------------------------------------
// LN over 1024-wide rows: x = z + v(residual); ddof=1, eps outside sqrt.
template<bool ZB>
__global__ __launch_bounds__(256) void ln_kernel(
    const void* zin, const float* __restrict__ vres,
    const float* __restrict__ gamma, const float* __restrict__ beta,
    float* outp)
{
  __shared__ float red[16];
  const int row = blockIdx.x;
  const int tid = threadIdx.x;
  const size_t base = (size_t)row * 1024 + tid * 4;

  float4 rv = *(const float4*)&vres[base];
  float4 x;
  if (ZB) {
    bf16x4 zb4 = *(const bf16x4*)((const bf16*)zin + base);
    x.x = (float)zb4[0] + rv.x; x.y = (float)zb4[1] + rv.y;
    x.z = (float)zb4[2] + rv.z; x.w = (float)zb4[3] + rv.w;
  } else {
    float4 zf = *(const float4*)((const float*)zin + base);
    x.x = zf.x + rv.x; x.y = zf.y + rv.y; x.z = zf.z + rv.z; x.w = zf.w + rv.w;
  }

  float s  = x.x + x.y + x.z + x.w;
  float ss = x.x * x.x + x.y * x.y + x.z * x.z + x.w * x.w;
  #pragma unroll
  for (int m = 32; m >= 1; m >>= 1) {
    s  += __shfl_xor(s,  m, 64);
    ss += __shfl_xor(ss, m, 64);
  }
  const int wave = tid >> 6, lane = tid & 63;
  if (lane == 0) { red[wave] = s; red[wave + 8] = ss; }
  __syncthreads();
  float S  = red[0] + red[1] + red[2] + red[3];
  float SS = red[8] + red[9] + red[10] + red[11];
  float mu  = S * (1.0f / 1024.0f);
  float var = (SS - 1024.0f * mu * mu) * (1.0f / 1023.0f);
  var = var < 0.0f ? 0.0f : var;
  float rs = 1.0f / (sqrtf(var) + 1e-3f);
  float4 gmv = *(const float4*)&gamma[tid * 4];
  float4 be  = *(const float4*)&beta[tid * 4];
  float4 y;
  y.x = (x.x - mu) * rs * gmv.x + be.x;
  y.y = (x.y - mu) * rs * gmv.y + be.y;
  y.z = (x.z - mu) * rs * gmv.z + be.z;
  y.w = (x.w - mu) * rs * gmv.w + be.w;
  *(float4*)&outp[base] = y;
}

// ---------------------------------------------------------------------------
extern "C" void kernel_launch(void* const* d_in, const int* in_sizes, int n_in,
                              void* d_out, int out_size, void* d_ws, size_t ws_size,
                              hipStream_t stream) {
  const float* v     = (const float*)d_in[2];
  const float* wvs   = (const float*)d_in[5];
  const float* pw    = (const float*)d_in[6];
  const float* pb    = (const float*)d_in[7];
  const float* gamma = (const float*)d_in[8];
  const float* beta  = (const float*)d_in[9];
  float* out = (float*)d_out;

  // ws: PW bf16 16M | WvT bf16 2M | A2 bf16 8M | x bf16 64M
  const size_t OFF_WVT = 16777216;
  const size_t OFF_A2  = OFF_WVT + 2097152;
  const size_t OFF_X   = OFF_A2 + 8388608;
  const size_t NEED_ZB = OFF_X + 67108864;

  bf16* PWb = (bf16*)d_ws;
  bf16* WvT = (bf16*)((char*)d_ws + OFF_WVT);
  bf16* A2  = (bf16*)((char*)d_ws + OFF_A2);
  const bool zb = (ws_size >= NEED_ZB);
  void* xbuf = zb ? (void*)((char*)d_ws + OFF_X) : (void*)out;

  hipLaunchKernelGGL(prep_pw_kernel,    dim3(8192), dim3(256), 0, stream, pw, PWb);
  hipLaunchKernelGGL(prep_wvt_kernel,   dim3(4096), dim3(256), 0, stream, wvs, WvT);
  hipLaunchKernelGGL(fill_attns_kernel, dim3(128),  dim3(256), 0, stream, out);
  hipLaunchKernelGGL(gemm1_kernel, dim3(64, 8), dim3(256), 0, stream, v, WvT, A2);
  if (zb) {
    hipLaunchKernelGGL((gemm2p8_kernel<true>),  dim3(512), dim3(512), 0, stream, A2, PWb, pb, xbuf);
    hipLaunchKernelGGL((ln_kernel<true>),       dim3(32768), dim3(256), 0, stream, xbuf, v, gamma, beta, out);
  } else {
    hipLaunchKernelGGL((gemm2p8_kernel<false>), dim3(512), dim3(512), 0, stream, A2, PWb, pb, xbuf);
    hipLaunchKernelGGL((ln_kernel<false>),      dim3(32768), dim3(256), 0, stream, xbuf, v, gamma, beta, out);
  }
}